// Round 11
// baseline (60.525 us; speedup 1.0000x reference)
//
#include <hip/hip_runtime.h>
#include <hip/hip_bf16.h>

// LengthRegulator: x [B=32,T=512,D=512] f32, duration [B,T] int32, max_len=4096.
// out0: [B,ML,D] f32, out1: mel_len [B] f32.
//
// R10 lesson: separate scan kernel = ~5us serialization bubble; R7's fused
// barrier-ful scan starved stores. R11: single kernel, BARRIER-FREE wave-
// redundant in-register scan (lane l holds csum[8l..8l+7] via int4 loads +
// in-lane prefix + 6-step shfl scan; needed values extracted via __shfl).
// ~0.3us VALU per block, hides under other blocks' store streams.
// Grid: expand blocks (64 phonemes, 8/wave) FIRST, then 128KB zerofill chunks.

typedef float f32x4 __attribute__((ext_vector_type(4)));

constexpr int B   = 32;
constexpr int T   = 512;
constexpr int D   = 512;
constexpr int D4  = D / 4;        // 128 x 16B per row
constexpr int ML  = 4096;
constexpr int NTHREADS = 512;
constexpr int kNumE   = 8;                 // expand blocks / batch (64 phonemes each)
constexpr int kZChunk = 64;                // frames per zerofill block (128KB)
constexpr int kNumZ   = ML / kZChunk;      // 64 zerofill blocks / batch

__global__ __launch_bounds__(NTHREADS) void lr_all(
    const int*   __restrict__ duration,  // [B, T]
    const f32x4* __restrict__ x,         // [B, T, D4]
    f32x4*       __restrict__ out,       // [B, ML, D4]
    float*       __restrict__ mel_out)   // [B]
{
    const int bid  = blockIdx.x;
    const bool isE = bid < B * kNumE;
    const int b    = isE ? bid / kNumE : (bid - B * kNumE) / kNumZ;
    const int r    = isE ? bid % kNumE : (bid - B * kNumE) % kNumZ;
    const int t    = threadIdx.x;
    const int lane = t & 63;
    const int wave = t >> 6;

    // ---- barrier-free in-register csum (each wave redundantly) ----
    // lane l holds csum[8l .. 8l+7]
    const int4* d4p = (const int4*)(duration + b * T);
    const int4 a = d4p[2 * lane];
    const int4 c = d4p[2 * lane + 1];
    int p0 = a.x,      p1 = p0 + a.y, p2 = p1 + a.z, p3 = p2 + a.w;
    int p4 = p3 + c.x, p5 = p4 + c.y, p6 = p5 + c.z, p7 = p6 + c.w;
    int s = p7;
    #pragma unroll
    for (int off = 1; off < 64; off <<= 1) {
        int n = __shfl_up(s, off, 64);
        if (lane >= off) s += n;
    }
    const int excl = s - p7;   // exclusive prefix of this lane's 8-sum
    p0 += excl; p1 += excl; p2 += excl; p3 += excl;
    p4 += excl; p5 += excl; p6 += excl; p7 += excl;

    const int mel = __shfl(p7, 63, 64);

    if (isE) {
        // ---- expand: wave w owns phonemes [64r+8w, +8) = lane Lsrc's regs ----
        const int Lsrc = 8 * r + wave;
        int e[8];
        e[0] = __shfl(p0, Lsrc, 64); e[1] = __shfl(p1, Lsrc, 64);
        e[2] = __shfl(p2, Lsrc, 64); e[3] = __shfl(p3, Lsrc, 64);
        e[4] = __shfl(p4, Lsrc, 64); e[5] = __shfl(p5, Lsrc, 64);
        e[6] = __shfl(p6, Lsrc, 64); e[7] = __shfl(p7, Lsrc, 64);
        const int sprev = __shfl(p7, (Lsrc == 0) ? 0 : Lsrc - 1, 64);
        int start0 = (Lsrc == 0) ? 0 : sprev;

        if (r == 0 && t == 0)
            mel_out[b] = (float)mel;

        const int pbase = 64 * r + 8 * wave;
        int st = start0;
        #pragma unroll
        for (int k = 0; k < 8; ++k) {
            const int en = e[k];
            if (en > st) {
                const size_t xb = ((size_t)(b * T + pbase + k)) * D4;
                const f32x4 v0 = x[xb + lane];        // first 1KB of row
                const f32x4 v1 = x[xb + 64 + lane];   // second 1KB
                size_t o = ((size_t)(b * ML + st)) * D4;
                for (int j = st; j < en; ++j, o += D4) {
                    out[o + lane]      = v0;          // full-line 1KB stores
                    out[o + 64 + lane] = v1;
                }
            }
            st = en;
        }
    } else {
        // ---- zerofill: frames [max(j0, mel), j0 + kZChunk) ----
        const int j0 = r * kZChunk;
        const int lo = (j0 > mel) ? j0 : mel;
        const int hi = j0 + kZChunk;
        if (lo < hi) {
            const f32x4 zero = {0.f, 0.f, 0.f, 0.f};
            const size_t base = ((size_t)(b * ML + lo)) * D4;
            const int total = (hi - lo) * D4;
            for (int m = t; m < total; m += NTHREADS)
                out[base + m] = zero;
        }
    }
}

extern "C" void kernel_launch(void* const* d_in, const int* in_sizes, int n_in,
                              void* d_out, int out_size, void* d_ws, size_t ws_size,
                              hipStream_t stream) {
    const float* x   = (const float*)d_in[0];
    const int*   dur = (const int*)d_in[1];

    float* out     = (float*)d_out;                 // [B*ML*D] then [B]
    float* mel_out = out + (size_t)B * ML * D;

    lr_all<<<B * (kNumE + kNumZ), NTHREADS, 0, stream>>>(
        dur, (const f32x4*)x, (f32x4*)out, mel_out);
}